// Round 1
// baseline (6516.159 us; speedup 1.0000x reference)
//
#include <hip/hip_runtime.h>
#include <cstdint>
#include <cstddef>

#define NT 256
#define DFEAT 128

// ---------- degree / dinv ----------
__global__ void deg_init_k(float* __restrict__ dc, float* __restrict__ dt, int n) {
  int i = blockIdx.x * NT + threadIdx.x;
  if (i < n) { dc[i] = 1.0f; dt[i] = 1.0f; }   // self-loop contributes 1
}

__global__ void deg_count_k(const int* __restrict__ dst, int e, float* __restrict__ deg) {
  int i = blockIdx.x * NT + threadIdx.x;
  if (i < e) atomicAdd(&deg[dst[i]], 1.0f);
}

__global__ void dinv_k(float* __restrict__ dc, float* __restrict__ dt, int n) {
  int i = blockIdx.x * NT + threadIdx.x;
  if (i < n) { dc[i] = rsqrtf(dc[i]); dt[i] = rsqrtf(dt[i]); }
}

// ---------- t = dinv * (x @ W) ----------
// block = 256 threads, 8 rows/block, 32 threads per row each computing 4 cols.
// W (128x128 fp32 = 64KB) staged in LDS; 8 x-rows (4KB) staged in LDS.
__global__ __launch_bounds__(256) void gemm_scale_k(
    const float* __restrict__ x, const float* __restrict__ W,
    const float* __restrict__ dinv, float* __restrict__ t, int n) {
  __shared__ float Wl[DFEAT * DFEAT];
  __shared__ float xs[8 * DFEAT];
  int tid = threadIdx.x;

  const float4* W4 = (const float4*)W;
  float4* Wl4 = (float4*)Wl;
#pragma unroll
  for (int i = 0; i < 16; i++) Wl4[tid + NT * i] = W4[tid + NT * i];

  int row0 = blockIdx.x * 8;
  {
    // 8 rows * 128 floats = 256 float4, one per thread
    int r = tid >> 5;              // row within block
    int row = row0 + r;
    float4* xs4 = (float4*)xs;
    if (row < n) {
      const float4* x4 = (const float4*)(x + (size_t)row * DFEAT);
      xs4[tid] = x4[tid & 31];
    } else {
      xs4[tid] = make_float4(0.f, 0.f, 0.f, 0.f);
    }
  }
  __syncthreads();

  int r = tid >> 5;
  int c4 = (tid & 31) << 2;
  float4 acc = make_float4(0.f, 0.f, 0.f, 0.f);
#pragma unroll 8
  for (int k = 0; k < DFEAT; k++) {
    float xv = xs[r * DFEAT + k];
    float4 w = *(const float4*)&Wl[k * DFEAT + c4];
    acc.x = fmaf(xv, w.x, acc.x);
    acc.y = fmaf(xv, w.y, acc.y);
    acc.z = fmaf(xv, w.z, acc.z);
    acc.w = fmaf(xv, w.w, acc.w);
  }
  int row = row0 + r;
  if (row < n) {
    float s = dinv[row];
    acc.x *= s; acc.y *= s; acc.z *= s; acc.w *= s;
    *(float4*)&t[(size_t)row * DFEAT + c4] = acc;
  }
}

// ---------- out = dinv_c*t_c + dinv_t*t_t + b_c + b_t  (self-loops + biases) ----------
__global__ void init_out_k(const float* __restrict__ tc, const float* __restrict__ tt,
                           const float* __restrict__ dc, const float* __restrict__ dt,
                           const float* __restrict__ bc, const float* __restrict__ bt,
                           float* __restrict__ out, int n) {
  int gid = blockIdx.x * NT + threadIdx.x;   // one float4 per thread
  if (gid >= n * 32) return;
  int row = gid >> 5;
  int c4 = (gid & 31) << 2;
  float sc = dc[row], st = dt[row];
  float4 a = *(const float4*)&tc[(size_t)gid * 4];
  float4 b = *(const float4*)&tt[(size_t)gid * 4];
  float4 bcv = *(const float4*)&bc[c4];
  float4 btv = *(const float4*)&bt[c4];
  float4 o;
  o.x = fmaf(sc, a.x, fmaf(st, b.x, bcv.x + btv.x));
  o.y = fmaf(sc, a.y, fmaf(st, b.y, bcv.y + btv.y));
  o.z = fmaf(sc, a.z, fmaf(st, b.z, bcv.z + btv.z));
  o.w = fmaf(sc, a.w, fmaf(st, b.w, bcv.w + btv.w));
  *(float4*)&out[(size_t)gid * 4] = o;
}

// ---------- edge scatter: out[dst] += dinv[dst] * t[src], 32 threads/edge ----------
__global__ void scatter_k(const int* __restrict__ src, const int* __restrict__ dst, int e,
                          const float* __restrict__ t, const float* __restrict__ dinv,
                          float* __restrict__ out) {
  int gid = blockIdx.x * NT + threadIdx.x;
  if (gid >= e * 32) return;
  int ei = gid >> 5;
  int c4 = (gid & 31) << 2;
  int s = src[ei];
  int d = dst[ei];
  float sc = dinv[d];
  float4 v = *(const float4*)&t[(size_t)s * DFEAT + c4];
  float* o = out + (size_t)d * DFEAT + c4;
  atomicAdd(o + 0, sc * v.x);
  atomicAdd(o + 1, sc * v.y);
  atomicAdd(o + 2, sc * v.z);
  atomicAdd(o + 3, sc * v.w);
}

// ---------- in-place relu ----------
__global__ void relu_k(float* __restrict__ x, int n4) {
  int gid = blockIdx.x * NT + threadIdx.x;
  if (gid < n4) {
    float4 v = ((float4*)x)[gid];
    v.x = fmaxf(v.x, 0.f);
    v.y = fmaxf(v.y, 0.f);
    v.z = fmaxf(v.z, 0.f);
    v.w = fmaxf(v.w, 0.f);
    ((float4*)x)[gid] = v;
  }
}

extern "C" void kernel_launch(void* const* d_in, const int* in_sizes, int n_in,
                              void* d_out, int out_size, void* d_ws, size_t ws_size,
                              hipStream_t stream) {
  const float* x0 = (const float*)d_in[0];
  const int*   ei = (const int*)d_in[1];
  const int*   ci = (const int*)d_in[2];
  const float* Wc = (const float*)d_in[3];
  const float* bc = (const float*)d_in[4];
  const float* Wt = (const float*)d_in[5];
  const float* bt = (const float*)d_in[6];
  float* out = (float*)d_out;

  int n  = in_sizes[0] / DFEAT;     // 100000
  int E  = in_sizes[1] / 2;         // 600000
  int EC = in_sizes[2] / 2;         // 200000

  const int* e_src = ei;
  const int* e_dst = ei + E;
  const int* c_src = ci;
  const int* c_dst = ci + EC;

  float* ws = (float*)d_ws;
  float* t_c    = ws;                                  // n*128
  float* t_t    = ws + (size_t)n * DFEAT;              // n*128
  float* dinv_c = ws + (size_t)n * DFEAT * 2;          // n
  float* dinv_t = dinv_c + n;                          // n

  int nb_n   = (n + NT - 1) / NT;
  int nb_row = (n + 7) / 8;
  int nb_f4  = (n * 32 + NT - 1) / NT;

  // degrees (same graphs every layer -> once per launch)
  deg_init_k<<<nb_n, NT, 0, stream>>>(dinv_c, dinv_t, n);
  deg_count_k<<<(E + NT - 1) / NT, NT, 0, stream>>>(e_dst, E, dinv_c);
  deg_count_k<<<(EC + NT - 1) / NT, NT, 0, stream>>>(c_dst, EC, dinv_t);
  dinv_k<<<nb_n, NT, 0, stream>>>(dinv_c, dinv_t, n);

  const float* xin = x0;
  for (int i = 0; i < 4; i++) {
    gemm_scale_k<<<nb_row, NT, 0, stream>>>(xin, Wc + (size_t)i * DFEAT * DFEAT, dinv_c, t_c, n);
    gemm_scale_k<<<nb_row, NT, 0, stream>>>(xin, Wt + (size_t)i * DFEAT * DFEAT, dinv_t, t_t, n);
    init_out_k<<<nb_f4, NT, 0, stream>>>(t_c, t_t, dinv_c, dinv_t,
                                         bc + i * DFEAT, bt + i * DFEAT, out, n);
    scatter_k<<<(E * 32 + NT - 1) / NT, NT, 0, stream>>>(e_src, e_dst, E, t_c, dinv_c, out);
    scatter_k<<<(EC * 32 + NT - 1) / NT, NT, 0, stream>>>(c_src, c_dst, EC, t_t, dinv_t, out);
    if (i < 3) relu_k<<<nb_f4, NT, 0, stream>>>(out, n * 32);
    xin = out;
  }
}

// Round 2
// 1457.974 us; speedup vs baseline: 4.4693x; 4.4693x over previous
//
#include <hip/hip_runtime.h>
#include <cstdint>
#include <cstddef>

#define NT 256
#define DFEAT 128
#define SCAN_T 1024

// ---------- zero int array ----------
__global__ void zero_k(int* __restrict__ p, int n) {
  int i = blockIdx.x * NT + threadIdx.x;
  if (i < n) p[i] = 0;
}

// ---------- histogram of dst ----------
__global__ void hist_k(const int* __restrict__ dst, int e, int* __restrict__ cnt) {
  int i = blockIdx.x * NT + threadIdx.x;
  if (i < e) atomicAdd(&cnt[dst[i]], 1);
}

// ---------- single-block exclusive scan: cnt[0..n) -> rowptr[0..n] ----------
// gridDim.x = 2: block 0 scans conv, block 1 scans ctrl.
__global__ __launch_bounds__(SCAN_T) void scan_k(
    const int* __restrict__ cnt_c, int* __restrict__ rp_c, int n_c,
    const int* __restrict__ cnt_t, int* __restrict__ rp_t, int n_t) {
  const int* cnt = (blockIdx.x == 0) ? cnt_c : cnt_t;
  int* rp        = (blockIdx.x == 0) ? rp_c  : rp_t;
  int n          = (blockIdx.x == 0) ? n_c   : n_t;

  __shared__ int ls[SCAN_T];
  int t = threadIdx.x;
  int chunk = (n + SCAN_T - 1) / SCAN_T;
  int lo = t * chunk, hi = min(n, lo + chunk);

  int local = 0;
  for (int i = lo; i < hi; i++) local += cnt[i];
  ls[t] = local;
  __syncthreads();

  // Hillis-Steele inclusive scan over block sums
  for (int off = 1; off < SCAN_T; off <<= 1) {
    int v = (t >= off) ? ls[t - off] : 0;
    __syncthreads();
    ls[t] += v;
    __syncthreads();
  }

  int base = ls[t] - local;   // exclusive start of this thread's chunk
  for (int i = lo; i < hi; i++) {
    rp[i] = base;
    base += cnt[i];
  }
  if (t == SCAN_T - 1) rp[n] = ls[SCAN_T - 1];
}

// ---------- fill CSR: csr[rowptr[dst] + cursor[dst]++] = src ----------
__global__ void fill_k(const int* __restrict__ src, const int* __restrict__ dst, int e,
                       const int* __restrict__ rp, int* __restrict__ cursor,
                       int* __restrict__ csr) {
  int i = blockIdx.x * NT + threadIdx.x;
  if (i < e) {
    int d = dst[i];
    int pos = rp[d] + atomicAdd(&cursor[d], 1);
    csr[pos] = src[i];
  }
}

// ---------- dinv from rowptr (degree + self-loop) ----------
__global__ void dinv_k(const int* __restrict__ rp_c, float* __restrict__ dc,
                       const int* __restrict__ rp_t, float* __restrict__ dt, int n) {
  int i = blockIdx.x * NT + threadIdx.x;
  if (i < n) {
    dc[i] = rsqrtf((float)(rp_c[i + 1] - rp_c[i] + 1));
    dt[i] = rsqrtf((float)(rp_t[i + 1] - rp_t[i] + 1));
  }
}

// ---------- t = dinv * (x @ W) ----------
// 256 threads, 8 rows/block, 32 threads/row, 4 cols/thread; W staged in LDS.
__global__ __launch_bounds__(256) void gemm_scale_k(
    const float* __restrict__ x, const float* __restrict__ W,
    const float* __restrict__ dinv, float* __restrict__ t, int n) {
  __shared__ float Wl[DFEAT * DFEAT];
  __shared__ float xs[8 * DFEAT];
  int tid = threadIdx.x;

  const float4* W4 = (const float4*)W;
  float4* Wl4 = (float4*)Wl;
#pragma unroll
  for (int i = 0; i < 16; i++) Wl4[tid + NT * i] = W4[tid + NT * i];

  int row0 = blockIdx.x * 8;
  {
    int r = tid >> 5;
    int row = row0 + r;
    float4* xs4 = (float4*)xs;
    if (row < n) {
      const float4* x4 = (const float4*)(x + (size_t)row * DFEAT);
      xs4[tid] = x4[tid & 31];
    } else {
      xs4[tid] = make_float4(0.f, 0.f, 0.f, 0.f);
    }
  }
  __syncthreads();

  int r = tid >> 5;
  int c4 = (tid & 31) << 2;
  float4 acc = make_float4(0.f, 0.f, 0.f, 0.f);
#pragma unroll 8
  for (int k = 0; k < DFEAT; k++) {
    float xv = xs[r * DFEAT + k];
    float4 w = *(const float4*)&Wl[k * DFEAT + c4];
    acc.x = fmaf(xv, w.x, acc.x);
    acc.y = fmaf(xv, w.y, acc.y);
    acc.z = fmaf(xv, w.z, acc.z);
    acc.w = fmaf(xv, w.w, acc.w);
  }
  int row = row0 + r;
  if (row < n) {
    float s = dinv[row];
    acc.x *= s; acc.y *= s; acc.z *= s; acc.w *= s;
    *(float4*)&t[(size_t)row * DFEAT + c4] = acc;
  }
}

// ---------- fused aggregate: gather both graphs + self-loop + bias + relu ----------
// out[v] = dc[v]*(t_c[v] + sum t_c[csr_c]) + dt[v]*(t_t[v] + sum t_t[csr_t]) + bc + bt
// 32 threads per node (one float4 column chunk each), 8 nodes per block.
__global__ __launch_bounds__(256) void aggregate_k(
    const float* __restrict__ tc, const float* __restrict__ tt,
    const int* __restrict__ rpc, const int* __restrict__ csc,
    const int* __restrict__ rpt, const int* __restrict__ cst,
    const float* __restrict__ dc, const float* __restrict__ dt,
    const float* __restrict__ bc, const float* __restrict__ bt,
    float* __restrict__ out, int n, int do_relu) {
  int node = blockIdx.x * 8 + (threadIdx.x >> 5);
  if (node >= n) return;
  int lane = threadIdx.x & 31;
  int c4 = lane << 2;

  // conv graph
  float4 accc = *(const float4*)&tc[(size_t)node * DFEAT + c4];  // self
  {
    int s0 = rpc[node], s1 = rpc[node + 1];
    int deg = s1 - s0;
    for (int base = 0; base < deg; base += 32) {
      int sv = (base + lane < deg) ? csc[s0 + base + lane] : 0;
      int m = min(32, deg - base);
      for (int k = 0; k < m; k++) {
        int s = __shfl(sv, k, 32);
        float4 v = *(const float4*)&tc[(size_t)s * DFEAT + c4];
        accc.x += v.x; accc.y += v.y; accc.z += v.z; accc.w += v.w;
      }
    }
  }
  // ctrl graph
  float4 acct = *(const float4*)&tt[(size_t)node * DFEAT + c4];  // self
  {
    int s0 = rpt[node], s1 = rpt[node + 1];
    int deg = s1 - s0;
    for (int base = 0; base < deg; base += 32) {
      int sv = (base + lane < deg) ? cst[s0 + base + lane] : 0;
      int m = min(32, deg - base);
      for (int k = 0; k < m; k++) {
        int s = __shfl(sv, k, 32);
        float4 v = *(const float4*)&tt[(size_t)s * DFEAT + c4];
        acct.x += v.x; acct.y += v.y; acct.z += v.z; acct.w += v.w;
      }
    }
  }

  float sc = dc[node], st = dt[node];
  float4 bcv = *(const float4*)&bc[c4];
  float4 btv = *(const float4*)&bt[c4];
  float4 o;
  o.x = fmaf(sc, accc.x, fmaf(st, acct.x, bcv.x + btv.x));
  o.y = fmaf(sc, accc.y, fmaf(st, acct.y, bcv.y + btv.y));
  o.z = fmaf(sc, accc.z, fmaf(st, acct.z, bcv.z + btv.z));
  o.w = fmaf(sc, accc.w, fmaf(st, acct.w, bcv.w + btv.w));
  if (do_relu) {
    o.x = fmaxf(o.x, 0.f); o.y = fmaxf(o.y, 0.f);
    o.z = fmaxf(o.z, 0.f); o.w = fmaxf(o.w, 0.f);
  }
  *(float4*)&out[(size_t)node * DFEAT + c4] = o;
}

extern "C" void kernel_launch(void* const* d_in, const int* in_sizes, int n_in,
                              void* d_out, int out_size, void* d_ws, size_t ws_size,
                              hipStream_t stream) {
  const float* x0 = (const float*)d_in[0];
  const int*   ei = (const int*)d_in[1];
  const int*   ci = (const int*)d_in[2];
  const float* Wc = (const float*)d_in[3];
  const float* bc = (const float*)d_in[4];
  const float* Wt = (const float*)d_in[5];
  const float* bt = (const float*)d_in[6];
  float* out = (float*)d_out;

  int n  = in_sizes[0] / DFEAT;     // 100000
  int E  = in_sizes[1] / 2;         // 600000
  int EC = in_sizes[2] / 2;         // 200000

  const int* e_src = ei;
  const int* e_dst = ei + E;
  const int* c_src = ci;
  const int* c_dst = ci + EC;

  // workspace layout (floats first for 16B alignment of t buffers)
  float* ws = (float*)d_ws;
  float* t_c    = ws;                                  // n*128 f
  float* t_t    = t_c + (size_t)n * DFEAT;             // n*128 f
  float* dinv_c = t_t + (size_t)n * DFEAT;             // n f
  float* dinv_t = dinv_c + n;                          // n f
  int* cnt_c = (int*)(dinv_t + n);                     // n i (hist, then cursor)
  int* cnt_t = cnt_c + n;                              // n i
  int* rp_c  = cnt_t + n;                              // n+1 i
  int* rp_t  = rp_c + (n + 1);                         // n+1 i
  int* csr_c = rp_t + (n + 1);                         // E i
  int* csr_t = csr_c + E;                              // EC i

  int nb_n   = (n + NT - 1) / NT;
  int nb_row = (n + 7) / 8;
  int nb_e   = (E + NT - 1) / NT;
  int nb_ec  = (EC + NT - 1) / NT;

  // ---- build CSR once per launch (graphs identical across layers) ----
  zero_k<<<(2 * n + NT - 1) / NT, NT, 0, stream>>>(cnt_c, 2 * n);  // cnt_c & cnt_t contiguous
  hist_k<<<nb_e, NT, 0, stream>>>(e_dst, E, cnt_c);
  hist_k<<<nb_ec, NT, 0, stream>>>(c_dst, EC, cnt_t);
  scan_k<<<2, SCAN_T, 0, stream>>>(cnt_c, rp_c, n, cnt_t, rp_t, n);
  zero_k<<<(2 * n + NT - 1) / NT, NT, 0, stream>>>(cnt_c, 2 * n);  // reuse as cursors
  fill_k<<<nb_e, NT, 0, stream>>>(e_src, e_dst, E, rp_c, cnt_c, csr_c);
  fill_k<<<nb_ec, NT, 0, stream>>>(c_src, c_dst, EC, rp_t, cnt_t, csr_t);
  dinv_k<<<nb_n, NT, 0, stream>>>(rp_c, dinv_c, rp_t, dinv_t, n);

  // ---- layers ----
  const float* xin = x0;
  for (int i = 0; i < 4; i++) {
    gemm_scale_k<<<nb_row, NT, 0, stream>>>(xin, Wc + (size_t)i * DFEAT * DFEAT, dinv_c, t_c, n);
    gemm_scale_k<<<nb_row, NT, 0, stream>>>(xin, Wt + (size_t)i * DFEAT * DFEAT, dinv_t, t_t, n);
    aggregate_k<<<nb_row, NT, 0, stream>>>(t_c, t_t, rp_c, csr_c, rp_t, csr_t,
                                           dinv_c, dinv_t, bc + i * DFEAT, bt + i * DFEAT,
                                           out, n, (i < 3) ? 1 : 0);
    xin = out;
  }
}

// Round 3
// 973.405 us; speedup vs baseline: 6.6942x; 1.4978x over previous
//
#include <hip/hip_runtime.h>
#include <cstdint>
#include <cstddef>

#define NT 256
#define DFEAT 128
#define GR 32            // rows per GEMM block
#define SCAN_ELEMS 1024  // elements per scan block (256 threads * 4)

// ---------- zero int array ----------
__global__ void zero_k(int* __restrict__ p, int n) {
  int i = blockIdx.x * NT + threadIdx.x;
  if (i < n) p[i] = 0;
}

// ---------- histogram of dst ----------
__global__ void hist_k(const int* __restrict__ dst, int e, int* __restrict__ cnt) {
  int i = blockIdx.x * NT + threadIdx.x;
  if (i < e) atomicAdd(&cnt[dst[i]], 1);
}

// ---------- scan pass A: per-block partial sums over both cnt arrays ----------
__global__ __launch_bounds__(NT) void scan_partial_k(
    const int* __restrict__ cnt_c, const int* __restrict__ cnt_t, int n,
    int* __restrict__ bsum, int nb_c) {
  int isT = blockIdx.x >= nb_c;
  const int* cnt = isT ? cnt_t : cnt_c;
  int b = isT ? blockIdx.x - nb_c : blockIdx.x;
  int base = b * SCAN_ELEMS + threadIdx.x * 4;

  int s = 0;
  if (base + 3 < n) {
    int4 v = *(const int4*)&cnt[base];
    s = v.x + v.y + v.z + v.w;
  } else {
    for (int j = 0; j < 4; j++) if (base + j < n) s += cnt[base + j];
  }
  // wave reduce (64) then LDS across 4 waves
  for (int off = 32; off > 0; off >>= 1) s += __shfl_down(s, off, 64);
  __shared__ int ws[4];
  int lane = threadIdx.x & 63, w = threadIdx.x >> 6;
  if (lane == 0) ws[w] = s;
  __syncthreads();
  if (threadIdx.x == 0) bsum[blockIdx.x] = ws[0] + ws[1] + ws[2] + ws[3];
}

// ---------- scan pass B: exclusive-scan block sums per segment; write rp[n] ----------
// grid = 2 blocks: block 0 -> conv segment, block 1 -> ctrl segment. nb <= 256.
__global__ __launch_bounds__(NT) void scan_offsets_k(
    int* __restrict__ bsum, int nb_c, int nb_t,
    int* __restrict__ rp_c, int* __restrict__ rp_t, int n) {
  int seg_off = (blockIdx.x == 0) ? 0 : nb_c;
  int nb = (blockIdx.x == 0) ? nb_c : nb_t;
  int* rp = (blockIdx.x == 0) ? rp_c : rp_t;

  __shared__ int ls[NT];
  int t = threadIdx.x;
  int v = (t < nb) ? bsum[seg_off + t] : 0;
  ls[t] = v;
  __syncthreads();
  for (int off = 1; off < NT; off <<= 1) {
    int u = (t >= off) ? ls[t - off] : 0;
    __syncthreads();
    ls[t] += u;
    __syncthreads();
  }
  if (t < nb) bsum[seg_off + t] = ls[t] - v;   // exclusive
  if (t == nb - 1) rp[n] = ls[t];              // total
}

// ---------- scan pass C: intra-block scan + offset -> rowptr ----------
__global__ __launch_bounds__(NT) void scan_final_k(
    const int* __restrict__ cnt_c, const int* __restrict__ cnt_t, int n,
    const int* __restrict__ bsum, int nb_c,
    int* __restrict__ rp_c, int* __restrict__ rp_t) {
  int isT = blockIdx.x >= nb_c;
  const int* cnt = isT ? cnt_t : cnt_c;
  int* rp = isT ? rp_t : rp_c;
  int b = isT ? blockIdx.x - nb_c : blockIdx.x;
  int offset = bsum[blockIdx.x];
  int base = b * SCAN_ELEMS + threadIdx.x * 4;

  int4 v = make_int4(0, 0, 0, 0);
  if (base + 3 < n) v = *(const int4*)&cnt[base];
  else { if (base + 0 < n) v.x = cnt[base + 0];
         if (base + 1 < n) v.y = cnt[base + 1];
         if (base + 2 < n) v.z = cnt[base + 2];
         if (base + 3 < n) v.w = cnt[base + 3]; }
  int tsum = v.x + v.y + v.z + v.w;

  __shared__ int ls[NT];
  int t = threadIdx.x;
  ls[t] = tsum;
  __syncthreads();
  for (int off = 1; off < NT; off <<= 1) {
    int u = (t >= off) ? ls[t - off] : 0;
    __syncthreads();
    ls[t] += u;
    __syncthreads();
  }
  int excl = offset + ls[t] - tsum;

  int4 o;
  o.x = excl;
  o.y = o.x + v.x;
  o.z = o.y + v.y;
  o.w = o.z + v.z;
  if (base + 3 < n) *(int4*)&rp[base] = o;
  else { if (base + 0 < n) rp[base + 0] = o.x;
         if (base + 1 < n) rp[base + 1] = o.y;
         if (base + 2 < n) rp[base + 2] = o.z;
         if (base + 3 < n) rp[base + 3] = o.w; }
}

// ---------- fill CSR ----------
__global__ void fill_k(const int* __restrict__ src, const int* __restrict__ dst, int e,
                       const int* __restrict__ rp, int* __restrict__ cursor,
                       int* __restrict__ csr) {
  int i = blockIdx.x * NT + threadIdx.x;
  if (i < e) {
    int d = dst[i];
    int pos = rp[d] + atomicAdd(&cursor[d], 1);
    csr[pos] = src[i];
  }
}

// ---------- dinv from rowptr (degree + self-loop) ----------
__global__ void dinv_k(const int* __restrict__ rp_c, float* __restrict__ dc,
                       const int* __restrict__ rp_t, float* __restrict__ dt, int n) {
  int i = blockIdx.x * NT + threadIdx.x;
  if (i < n) {
    dc[i] = rsqrtf((float)(rp_c[i + 1] - rp_c[i] + 1));
    dt[i] = rsqrtf((float)(rp_t[i + 1] - rp_t[i] + 1));
  }
}

// ---------- t = dinv * (x @ W), register-tiled 4x4 ----------
// 256 threads, 32 rows/block. Thread (rg=tid>>5, c=tid&31) computes rows
// rg*4..rg*4+3 x cols c*4..c*4+3. x staged TRANSPOSED in LDS so the k-loop
// is 2x ds_read_b128 (both broadcast / 2-way aliased = conflict-free) + 16 FMA.
__global__ __launch_bounds__(256) void gemm_scale_k(
    const float* __restrict__ x, const float* __restrict__ W,
    const float* __restrict__ dinv, float* __restrict__ t, int n) {
  __shared__ float Wl[DFEAT * DFEAT];   // 64 KB
  __shared__ float xsT[DFEAT * GR];     // 16 KB, [k][r]
  int tid = threadIdx.x;

  const float4* W4 = (const float4*)W;
  float4* Wl4 = (float4*)Wl;
#pragma unroll
  for (int i = 0; i < 16; i++) Wl4[tid + NT * i] = W4[tid + NT * i];

  int row0 = blockIdx.x * GR;
  {
    int r = tid & 31;
    int kc0 = tid >> 5;         // 0..7
    int row = row0 + r;
#pragma unroll
    for (int it = 0; it < 4; it++) {
      int kc = kc0 + it * 8;    // 0..31 -> k = kc*4
      float4 v = make_float4(0.f, 0.f, 0.f, 0.f);
      if (row < n) v = *(const float4*)&x[(size_t)row * DFEAT + kc * 4];
      xsT[(kc * 4 + 0) * GR + r] = v.x;
      xsT[(kc * 4 + 1) * GR + r] = v.y;
      xsT[(kc * 4 + 2) * GR + r] = v.z;
      xsT[(kc * 4 + 3) * GR + r] = v.w;
    }
  }
  __syncthreads();

  int c4 = (tid & 31) << 2;
  int r0 = (tid >> 5) << 2;
  float4 acc0 = make_float4(0.f, 0.f, 0.f, 0.f);
  float4 acc1 = acc0, acc2 = acc0, acc3 = acc0;

#pragma unroll 4
  for (int k = 0; k < DFEAT; k++) {
    float4 xv = *(const float4*)&xsT[k * GR + r0];
    float4 wv = *(const float4*)&Wl[k * DFEAT + c4];
    acc0.x = fmaf(xv.x, wv.x, acc0.x); acc0.y = fmaf(xv.x, wv.y, acc0.y);
    acc0.z = fmaf(xv.x, wv.z, acc0.z); acc0.w = fmaf(xv.x, wv.w, acc0.w);
    acc1.x = fmaf(xv.y, wv.x, acc1.x); acc1.y = fmaf(xv.y, wv.y, acc1.y);
    acc1.z = fmaf(xv.y, wv.z, acc1.z); acc1.w = fmaf(xv.y, wv.w, acc1.w);
    acc2.x = fmaf(xv.z, wv.x, acc2.x); acc2.y = fmaf(xv.z, wv.y, acc2.y);
    acc2.z = fmaf(xv.z, wv.z, acc2.z); acc2.w = fmaf(xv.z, wv.w, acc2.w);
    acc3.x = fmaf(xv.w, wv.x, acc3.x); acc3.y = fmaf(xv.w, wv.y, acc3.y);
    acc3.z = fmaf(xv.w, wv.z, acc3.z); acc3.w = fmaf(xv.w, wv.w, acc3.w);
  }

  float4 accs[4] = {acc0, acc1, acc2, acc3};
#pragma unroll
  for (int i = 0; i < 4; i++) {
    int row = row0 + r0 + i;
    if (row < n) {
      float s = dinv[row];
      float4 a = accs[i];
      a.x *= s; a.y *= s; a.z *= s; a.w *= s;
      *(float4*)&t[(size_t)row * DFEAT + c4] = a;
    }
  }
}

// ---------- fused aggregate: gather both graphs + self-loop + bias + relu ----------
__global__ __launch_bounds__(256) void aggregate_k(
    const float* __restrict__ tc, const float* __restrict__ tt,
    const int* __restrict__ rpc, const int* __restrict__ csc,
    const int* __restrict__ rpt, const int* __restrict__ cst,
    const float* __restrict__ dc, const float* __restrict__ dt,
    const float* __restrict__ bc, const float* __restrict__ bt,
    float* __restrict__ out, int n, int do_relu) {
  int node = blockIdx.x * 8 + (threadIdx.x >> 5);
  if (node >= n) return;
  int lane = threadIdx.x & 31;
  int c4 = lane << 2;

  float4 accc = *(const float4*)&tc[(size_t)node * DFEAT + c4];  // self
  {
    int s0 = rpc[node], s1 = rpc[node + 1];
    int deg = s1 - s0;
    for (int base = 0; base < deg; base += 32) {
      int sv = (base + lane < deg) ? csc[s0 + base + lane] : 0;
      int m = min(32, deg - base);
      for (int k = 0; k < m; k++) {
        int s = __shfl(sv, k, 32);
        float4 v = *(const float4*)&tc[(size_t)s * DFEAT + c4];
        accc.x += v.x; accc.y += v.y; accc.z += v.z; accc.w += v.w;
      }
    }
  }
  float4 acct = *(const float4*)&tt[(size_t)node * DFEAT + c4];  // self
  {
    int s0 = rpt[node], s1 = rpt[node + 1];
    int deg = s1 - s0;
    for (int base = 0; base < deg; base += 32) {
      int sv = (base + lane < deg) ? cst[s0 + base + lane] : 0;
      int m = min(32, deg - base);
      for (int k = 0; k < m; k++) {
        int s = __shfl(sv, k, 32);
        float4 v = *(const float4*)&tt[(size_t)s * DFEAT + c4];
        acct.x += v.x; acct.y += v.y; acct.z += v.z; acct.w += v.w;
      }
    }
  }

  float sc = dc[node], st = dt[node];
  float4 bcv = *(const float4*)&bc[c4];
  float4 btv = *(const float4*)&bt[c4];
  float4 o;
  o.x = fmaf(sc, accc.x, fmaf(st, acct.x, bcv.x + btv.x));
  o.y = fmaf(sc, accc.y, fmaf(st, acct.y, bcv.y + btv.y));
  o.z = fmaf(sc, accc.z, fmaf(st, acct.z, bcv.z + btv.z));
  o.w = fmaf(sc, accc.w, fmaf(st, acct.w, bcv.w + btv.w));
  if (do_relu) {
    o.x = fmaxf(o.x, 0.f); o.y = fmaxf(o.y, 0.f);
    o.z = fmaxf(o.z, 0.f); o.w = fmaxf(o.w, 0.f);
  }
  *(float4*)&out[(size_t)node * DFEAT + c4] = o;
}

extern "C" void kernel_launch(void* const* d_in, const int* in_sizes, int n_in,
                              void* d_out, int out_size, void* d_ws, size_t ws_size,
                              hipStream_t stream) {
  const float* x0 = (const float*)d_in[0];
  const int*   ei = (const int*)d_in[1];
  const int*   ci = (const int*)d_in[2];
  const float* Wc = (const float*)d_in[3];
  const float* bc = (const float*)d_in[4];
  const float* Wt = (const float*)d_in[5];
  const float* bt = (const float*)d_in[6];
  float* out = (float*)d_out;

  int n  = in_sizes[0] / DFEAT;     // 100000
  int E  = in_sizes[1] / 2;         // 600000
  int EC = in_sizes[2] / 2;         // 200000

  const int* e_src = ei;
  const int* e_dst = ei + E;
  const int* c_src = ci;
  const int* c_dst = ci + EC;

  float* ws = (float*)d_ws;
  float* t_c    = ws;                                  // n*128 f
  float* t_t    = t_c + (size_t)n * DFEAT;             // n*128 f
  float* dinv_c = t_t + (size_t)n * DFEAT;             // n f
  float* dinv_t = dinv_c + n;                          // n f
  int* cnt_c = (int*)(dinv_t + n);                     // n i (hist, then cursor)
  int* cnt_t = cnt_c + n;                              // n i
  int* rp_c  = cnt_t + n;                              // n+1 i
  int* rp_t  = rp_c + (n + 1);                         // n+1 i
  int* csr_c = rp_t + (n + 1);                         // E i
  int* csr_t = csr_c + E;                              // EC i
  int* bsum  = csr_t + EC;                             // nb_c + nb_t i

  int nb_n    = (n + NT - 1) / NT;
  int nb_node = (n + 7) / 8;
  int nb_gemm = (n + GR - 1) / GR;
  int nb_e    = (E + NT - 1) / NT;
  int nb_ec   = (EC + NT - 1) / NT;
  int nb_scan = (n + SCAN_ELEMS - 1) / SCAN_ELEMS;     // 98 (<=256 required)

  // ---- build CSR once per launch ----
  zero_k<<<(2 * n + NT - 1) / NT, NT, 0, stream>>>(cnt_c, 2 * n);
  hist_k<<<nb_e, NT, 0, stream>>>(e_dst, E, cnt_c);
  hist_k<<<nb_ec, NT, 0, stream>>>(c_dst, EC, cnt_t);
  scan_partial_k<<<2 * nb_scan, NT, 0, stream>>>(cnt_c, cnt_t, n, bsum, nb_scan);
  scan_offsets_k<<<2, NT, 0, stream>>>(bsum, nb_scan, nb_scan, rp_c, rp_t, n);
  scan_final_k<<<2 * nb_scan, NT, 0, stream>>>(cnt_c, cnt_t, n, bsum, nb_scan, rp_c, rp_t);
  zero_k<<<(2 * n + NT - 1) / NT, NT, 0, stream>>>(cnt_c, 2 * n);  // cursors
  fill_k<<<nb_e, NT, 0, stream>>>(e_src, e_dst, E, rp_c, cnt_c, csr_c);
  fill_k<<<nb_ec, NT, 0, stream>>>(c_src, c_dst, EC, rp_t, cnt_t, csr_t);
  dinv_k<<<nb_n, NT, 0, stream>>>(rp_c, dinv_c, rp_t, dinv_t, n);

  // ---- layers ----
  const float* xin = x0;
  for (int i = 0; i < 4; i++) {
    gemm_scale_k<<<nb_gemm, NT, 0, stream>>>(xin, Wc + (size_t)i * DFEAT * DFEAT, dinv_c, t_c, n);
    gemm_scale_k<<<nb_gemm, NT, 0, stream>>>(xin, Wt + (size_t)i * DFEAT * DFEAT, dinv_t, t_t, n);
    aggregate_k<<<nb_node, NT, 0, stream>>>(t_c, t_t, rp_c, csr_c, rp_t, csr_t,
                                            dinv_c, dinv_t, bc + i * DFEAT, bt + i * DFEAT,
                                            out, n, (i < 3) ? 1 : 0);
    xin = out;
  }
}

// Round 4
// 512.493 us; speedup vs baseline: 12.7146x; 1.8994x over previous
//
#include <hip/hip_runtime.h>
#include <cstdint>
#include <cstddef>

#define NT 256
#define DFEAT 128
#define SCAN_ELEMS 1024
#define GEMM_ROWS 64
#define BPAD 136   // padded LDS k-stride (ushorts) for W^T tiles: breaks 16-way bank conflict

typedef __attribute__((ext_vector_type(8))) short s8v;
typedef __attribute__((ext_vector_type(4))) float f32x4;

__device__ inline ushort f2bf(float f) {           // RNE fp32 -> bf16
  uint32_t u = __float_as_uint(f);
  u += 0x7fffu + ((u >> 16) & 1u);
  return (ushort)(u >> 16);
}
__device__ inline void acc_bf4(uint2 v, float& a0, float& a1, float& a2, float& a3) {
  a0 += __uint_as_float(v.x << 16);
  a1 += __uint_as_float(v.x & 0xffff0000u);
  a2 += __uint_as_float(v.y << 16);
  a3 += __uint_as_float(v.y & 0xffff0000u);
}

// ---------- zero int array ----------
__global__ void zero_k(int* __restrict__ p, int n) {
  int i = blockIdx.x * NT + threadIdx.x;
  if (i < n) p[i] = 0;
}

// ---------- histogram of dst ----------
__global__ void hist_k(const int* __restrict__ dst, int e, int* __restrict__ cnt) {
  int i = blockIdx.x * NT + threadIdx.x;
  if (i < e) atomicAdd(&cnt[dst[i]], 1);
}

// ---------- scan pass A ----------
__global__ __launch_bounds__(NT) void scan_partial_k(
    const int* __restrict__ cnt_c, const int* __restrict__ cnt_t, int n,
    int* __restrict__ bsum, int nb_c) {
  int isT = blockIdx.x >= nb_c;
  const int* cnt = isT ? cnt_t : cnt_c;
  int b = isT ? blockIdx.x - nb_c : blockIdx.x;
  int base = b * SCAN_ELEMS + threadIdx.x * 4;

  int s = 0;
  if (base + 3 < n) {
    int4 v = *(const int4*)&cnt[base];
    s = v.x + v.y + v.z + v.w;
  } else {
    for (int j = 0; j < 4; j++) if (base + j < n) s += cnt[base + j];
  }
  for (int off = 32; off > 0; off >>= 1) s += __shfl_down(s, off, 64);
  __shared__ int ws[4];
  int lane = threadIdx.x & 63, w = threadIdx.x >> 6;
  if (lane == 0) ws[w] = s;
  __syncthreads();
  if (threadIdx.x == 0) bsum[blockIdx.x] = ws[0] + ws[1] + ws[2] + ws[3];
}

// ---------- scan pass B ----------
__global__ __launch_bounds__(NT) void scan_offsets_k(
    int* __restrict__ bsum, int nb_c, int nb_t,
    int* __restrict__ rp_c, int* __restrict__ rp_t, int n) {
  int seg_off = (blockIdx.x == 0) ? 0 : nb_c;
  int nb = (blockIdx.x == 0) ? nb_c : nb_t;
  int* rp = (blockIdx.x == 0) ? rp_c : rp_t;

  __shared__ int ls[NT];
  int t = threadIdx.x;
  int v = (t < nb) ? bsum[seg_off + t] : 0;
  ls[t] = v;
  __syncthreads();
  for (int off = 1; off < NT; off <<= 1) {
    int u = (t >= off) ? ls[t - off] : 0;
    __syncthreads();
    ls[t] += u;
    __syncthreads();
  }
  if (t < nb) bsum[seg_off + t] = ls[t] - v;
  if (t == nb - 1) rp[n] = ls[t];
}

// ---------- scan pass C ----------
__global__ __launch_bounds__(NT) void scan_final_k(
    const int* __restrict__ cnt_c, const int* __restrict__ cnt_t, int n,
    const int* __restrict__ bsum, int nb_c,
    int* __restrict__ rp_c, int* __restrict__ rp_t) {
  int isT = blockIdx.x >= nb_c;
  const int* cnt = isT ? cnt_t : cnt_c;
  int* rp = isT ? rp_t : rp_c;
  int b = isT ? blockIdx.x - nb_c : blockIdx.x;
  int offset = bsum[blockIdx.x];
  int base = b * SCAN_ELEMS + threadIdx.x * 4;

  int4 v = make_int4(0, 0, 0, 0);
  if (base + 3 < n) v = *(const int4*)&cnt[base];
  else { if (base + 0 < n) v.x = cnt[base + 0];
         if (base + 1 < n) v.y = cnt[base + 1];
         if (base + 2 < n) v.z = cnt[base + 2];
         if (base + 3 < n) v.w = cnt[base + 3]; }
  int tsum = v.x + v.y + v.z + v.w;

  __shared__ int ls[NT];
  int t = threadIdx.x;
  ls[t] = tsum;
  __syncthreads();
  for (int off = 1; off < NT; off <<= 1) {
    int u = (t >= off) ? ls[t - off] : 0;
    __syncthreads();
    ls[t] += u;
    __syncthreads();
  }
  int excl = offset + ls[t] - tsum;

  int4 o;
  o.x = excl;
  o.y = o.x + v.x;
  o.z = o.y + v.y;
  o.w = o.z + v.z;
  if (base + 3 < n) *(int4*)&rp[base] = o;
  else { if (base + 0 < n) rp[base + 0] = o.x;
         if (base + 1 < n) rp[base + 1] = o.y;
         if (base + 2 < n) rp[base + 2] = o.z;
         if (base + 3 < n) rp[base + 3] = o.w; }
}

// ---------- fill CSR ----------
__global__ void fill_k(const int* __restrict__ src, const int* __restrict__ dst, int e,
                       const int* __restrict__ rp, int* __restrict__ cursor,
                       int* __restrict__ csr) {
  int i = blockIdx.x * NT + threadIdx.x;
  if (i < e) {
    int d = dst[i];
    int pos = rp[d] + atomicAdd(&cursor[d], 1);
    csr[pos] = src[i];
  }
}

// ---------- dinv ----------
__global__ void dinv_k(const int* __restrict__ rp_c, float* __restrict__ dc,
                       const int* __restrict__ rp_t, float* __restrict__ dt, int n) {
  int i = blockIdx.x * NT + threadIdx.x;
  if (i < n) {
    dc[i] = rsqrtf((float)(rp_c[i + 1] - rp_c[i] + 1));
    dt[i] = rsqrtf((float)(rp_t[i + 1] - rp_t[i] + 1));
  }
}

// ---------- x fp32 -> bf16 ----------
__global__ void convx_k(const float* __restrict__ x, ushort* __restrict__ xh, int total4) {
  int i = blockIdx.x * NT + threadIdx.x;
  if (i < total4) {
    float4 v = ((const float4*)x)[i];
    ushort4 o;
    o.x = f2bf(v.x); o.y = f2bf(v.y); o.z = f2bf(v.z); o.w = f2bf(v.w);
    ((ushort4*)xh)[i] = o;
  }
}

// ---------- W fp32 [l][k][c] -> bf16 transposed wT[l][c][k] (8 matrices) ----------
__global__ void convw_k(const float* __restrict__ Wc, const float* __restrict__ Wt,
                        ushort* __restrict__ wT) {
  int gid = blockIdx.x * NT + threadIdx.x;      // 8*128*128 total
  int l = gid >> 14, rem = gid & 16383;
  int c = rem >> 7, k = rem & 127;
  const float* W = (l < 4) ? (Wc + (size_t)l * 16384) : (Wt + (size_t)(l - 4) * 16384);
  wT[gid] = f2bf(W[k * DFEAT + c]);
}

// ---------- fused dual GEMM: t_c = dinv_c*(x@Wc), t_t = dinv_t*(x@Wt), bf16 MFMA ----------
// 256 thr = 4 waves, 64 rows/block, each wave 16 rows x 128 cols.
// A-frag: lane l holds x[row0+(l&15)][(l>>4)*8+j+32ks] (direct global, single-use).
// B-frag: W^T in LDS [c][k], stride BPAD; lane reads [c8*16+(l&15)][(l>>4)*8+32ks..+8].
__global__ __launch_bounds__(256) void gemm2_k(
    const ushort* __restrict__ xh,
    const ushort* __restrict__ wTc, const ushort* __restrict__ wTt,
    const float* __restrict__ dinv_c, const float* __restrict__ dinv_t,
    ushort* __restrict__ t_c, ushort* __restrict__ t_t, int n) {
  __shared__ __align__(16) ushort Bc[DFEAT * BPAD];
  __shared__ __align__(16) ushort Bt[DFEAT * BPAD];
  int tid = threadIdx.x;

#pragma unroll
  for (int it = 0; it < 8; it++) {
    int idx = tid + it * NT;          // 0..2047: 128 rows x 16 uint4
    int c = idx >> 4, i = idx & 15;
    *(uint4*)&Bc[c * BPAD + i * 8] = *(const uint4*)&wTc[c * DFEAT + i * 8];
    *(uint4*)&Bt[c * BPAD + i * 8] = *(const uint4*)&wTt[c * DFEAT + i * 8];
  }
  __syncthreads();

  int wave = tid >> 6;
  int lane = tid & 63;
  int m = lane & 15;
  int q = lane >> 4;
  int row = blockIdx.x * GEMM_ROWS + wave * 16 + m;

  f32x4 zero4 = {0.f, 0.f, 0.f, 0.f};
  f32x4 accC[8], accT[8];
#pragma unroll
  for (int i = 0; i < 8; i++) { accC[i] = zero4; accT[i] = zero4; }

#pragma unroll
  for (int ks = 0; ks < 4; ks++) {
    uint4 av = make_uint4(0, 0, 0, 0);
    if (row < n) av = *(const uint4*)&xh[(size_t)row * DFEAT + ks * 32 + q * 8];
    union { uint4 u; s8v s; } ac; ac.u = av;
#pragma unroll
    for (int c8 = 0; c8 < 8; c8++) {
      s8v bC = *(const s8v*)&Bc[(c8 * 16 + m) * BPAD + ks * 32 + q * 8];
      s8v bT = *(const s8v*)&Bt[(c8 * 16 + m) * BPAD + ks * 32 + q * 8];
      accC[c8] = __builtin_amdgcn_mfma_f32_16x16x32_bf16(ac.s, bC, accC[c8], 0, 0, 0);
      accT[c8] = __builtin_amdgcn_mfma_f32_16x16x32_bf16(ac.s, bT, accT[c8], 0, 0, 0);
    }
  }

  // epilogue: D row=(q*4+r), col=c8*16+m
  int rbase = blockIdx.x * GEMM_ROWS + wave * 16 + q * 4;
#pragma unroll
  for (int r = 0; r < 4; r++) {
    int orow = rbase + r;
    if (orow < n) {
      float sc = dinv_c[orow], st = dinv_t[orow];
#pragma unroll
      for (int c8 = 0; c8 < 8; c8++) {
        int col = c8 * 16 + m;
        t_c[(size_t)orow * DFEAT + col] = f2bf(sc * accC[c8][r]);
        t_t[(size_t)orow * DFEAT + col] = f2bf(st * accT[c8][r]);
      }
    }
  }
}

// ---------- fused aggregate (bf16 in): both graphs + self + bias (+relu) ----------
// last==0: write bf16 xh (next layer input). last==1: write fp32 d_out.
__global__ __launch_bounds__(256) void aggregate_k(
    const ushort* __restrict__ tc, const ushort* __restrict__ tt,
    const int* __restrict__ rpc, const int* __restrict__ csc,
    const int* __restrict__ rpt, const int* __restrict__ cst,
    const float* __restrict__ dc, const float* __restrict__ dt,
    const float* __restrict__ bc, const float* __restrict__ bt,
    float* __restrict__ outf, ushort* __restrict__ outh, int n, int last) {
  int node = blockIdx.x * 8 + (threadIdx.x >> 5);
  if (node >= n) return;
  int lane = threadIdx.x & 31;
  int c4 = lane << 2;

  float a0 = 0.f, a1 = 0.f, a2 = 0.f, a3 = 0.f;   // conv acc
  acc_bf4(*(const uint2*)&tc[(size_t)node * DFEAT + c4], a0, a1, a2, a3);  // self
  {
    int s0 = rpc[node], s1 = rpc[node + 1];
    int deg = s1 - s0;
    for (int base = 0; base < deg; base += 32) {
      int sv = (base + lane < deg) ? csc[s0 + base + lane] : 0;
      int mm = min(32, deg - base);
      for (int k = 0; k < mm; k++) {
        int s = __shfl(sv, k, 32);
        acc_bf4(*(const uint2*)&tc[(size_t)s * DFEAT + c4], a0, a1, a2, a3);
      }
    }
  }
  float b0 = 0.f, b1 = 0.f, b2 = 0.f, b3 = 0.f;   // ctrl acc
  acc_bf4(*(const uint2*)&tt[(size_t)node * DFEAT + c4], b0, b1, b2, b3);  // self
  {
    int s0 = rpt[node], s1 = rpt[node + 1];
    int deg = s1 - s0;
    for (int base = 0; base < deg; base += 32) {
      int sv = (base + lane < deg) ? cst[s0 + base + lane] : 0;
      int mm = min(32, deg - base);
      for (int k = 0; k < mm; k++) {
        int s = __shfl(sv, k, 32);
        acc_bf4(*(const uint2*)&tt[(size_t)s * DFEAT + c4], b0, b1, b2, b3);
      }
    }
  }

  float sc = dc[node], st = dt[node];
  float4 bcv = *(const float4*)&bc[c4];
  float4 btv = *(const float4*)&bt[c4];
  float4 o;
  o.x = fmaf(sc, a0, fmaf(st, b0, bcv.x + btv.x));
  o.y = fmaf(sc, a1, fmaf(st, b1, bcv.y + btv.y));
  o.z = fmaf(sc, a2, fmaf(st, b2, bcv.z + btv.z));
  o.w = fmaf(sc, a3, fmaf(st, b3, bcv.w + btv.w));

  if (last) {
    *(float4*)&outf[(size_t)node * DFEAT + c4] = o;
  } else {
    ushort4 h;
    h.x = f2bf(fmaxf(o.x, 0.f));
    h.y = f2bf(fmaxf(o.y, 0.f));
    h.z = f2bf(fmaxf(o.z, 0.f));
    h.w = f2bf(fmaxf(o.w, 0.f));
    *(ushort4*)&outh[(size_t)node * DFEAT + c4] = h;
  }
}

extern "C" void kernel_launch(void* const* d_in, const int* in_sizes, int n_in,
                              void* d_out, int out_size, void* d_ws, size_t ws_size,
                              hipStream_t stream) {
  const float* x0 = (const float*)d_in[0];
  const int*   ei = (const int*)d_in[1];
  const int*   ci = (const int*)d_in[2];
  const float* Wc = (const float*)d_in[3];
  const float* bc = (const float*)d_in[4];
  const float* Wt = (const float*)d_in[5];
  const float* bt = (const float*)d_in[6];
  float* out = (float*)d_out;

  int n  = in_sizes[0] / DFEAT;     // 100000
  int E  = in_sizes[1] / 2;         // 600000
  int EC = in_sizes[2] / 2;         // 200000

  const int* e_src = ei;
  const int* e_dst = ei + E;
  const int* c_src = ci;
  const int* c_dst = ci + EC;

  // ---- workspace layout (all 16B-aligned where vector-accessed) ----
  char* p = (char*)d_ws;
  ushort* t_c = (ushort*)p; p += (size_t)n * DFEAT * 2;
  ushort* t_t = (ushort*)p; p += (size_t)n * DFEAT * 2;
  ushort* xh  = (ushort*)p; p += (size_t)n * DFEAT * 2;
  ushort* wT  = (ushort*)p; p += (size_t)8 * DFEAT * DFEAT * 2;
  float* dinv_c = (float*)p; p += (size_t)n * 4;
  float* dinv_t = (float*)p; p += (size_t)n * 4;
  int* cnt_c = (int*)p; p += (size_t)n * 4;
  int* cnt_t = (int*)p; p += (size_t)n * 4;
  int* rp_c  = (int*)p; p += (size_t)(n + 1) * 4;
  int* rp_t  = (int*)p; p += (size_t)(n + 1) * 4;
  int* csr_c = (int*)p; p += (size_t)E * 4;
  int* csr_t = (int*)p; p += (size_t)EC * 4;
  int* bsum  = (int*)p;

  int nb_n    = (n + NT - 1) / NT;
  int nb_node = (n + 7) / 8;
  int nb_gemm = (n + GEMM_ROWS - 1) / GEMM_ROWS;
  int nb_e    = (E + NT - 1) / NT;
  int nb_ec   = (EC + NT - 1) / NT;
  int nb_scan = (n + SCAN_ELEMS - 1) / SCAN_ELEMS;   // 98 (<=256 required)

  // ---- build CSR + dinv once per launch ----
  zero_k<<<(2 * n + NT - 1) / NT, NT, 0, stream>>>(cnt_c, 2 * n);
  hist_k<<<nb_e, NT, 0, stream>>>(e_dst, E, cnt_c);
  hist_k<<<nb_ec, NT, 0, stream>>>(c_dst, EC, cnt_t);
  scan_partial_k<<<2 * nb_scan, NT, 0, stream>>>(cnt_c, cnt_t, n, bsum, nb_scan);
  scan_offsets_k<<<2, NT, 0, stream>>>(bsum, nb_scan, nb_scan, rp_c, rp_t, n);
  scan_final_k<<<2 * nb_scan, NT, 0, stream>>>(cnt_c, cnt_t, n, bsum, nb_scan, rp_c, rp_t);
  zero_k<<<(2 * n + NT - 1) / NT, NT, 0, stream>>>(cnt_c, 2 * n);  // cursors
  fill_k<<<nb_e, NT, 0, stream>>>(e_src, e_dst, E, rp_c, cnt_c, csr_c);
  fill_k<<<nb_ec, NT, 0, stream>>>(c_src, c_dst, EC, rp_t, cnt_t, csr_t);
  dinv_k<<<nb_n, NT, 0, stream>>>(rp_c, dinv_c, rp_t, dinv_t, n);

  // ---- bf16 conversions ----
  convx_k<<<(n * 32 + NT - 1) / NT, NT, 0, stream>>>(x0, xh, n * 32);
  convw_k<<<(8 * DFEAT * DFEAT) / NT, NT, 0, stream>>>(Wc, Wt, wT);

  // ---- layers ----
  for (int i = 0; i < 4; i++) {
    gemm2_k<<<nb_gemm, NT, 0, stream>>>(xh,
                                        wT + (size_t)i * DFEAT * DFEAT,
                                        wT + (size_t)(4 + i) * DFEAT * DFEAT,
                                        dinv_c, dinv_t, t_c, t_t, n);
    aggregate_k<<<nb_node, NT, 0, stream>>>(t_c, t_t, rp_c, csr_c, rp_t, csr_t,
                                            dinv_c, dinv_t, bc + i * DFEAT, bt + i * DFEAT,
                                            out, xh, n, (i == 3) ? 1 : 0);
  }
}

// Round 5
// 476.651 us; speedup vs baseline: 13.6707x; 1.0752x over previous
//
#include <hip/hip_runtime.h>
#include <cstdint>
#include <cstddef>

#define NT 256
#define DFEAT 128
#define SCAN_ELEMS 1024
#define GEMM_ROWS 128    // rows per gemm block (4 waves x 32 rows)
#define BPAD 136         // padded LDS k-stride (ushorts) for W^T tiles

typedef __attribute__((ext_vector_type(8))) short s8v;
typedef __attribute__((ext_vector_type(4))) float f32x4;

__device__ inline ushort f2bf(float f) {           // RNE fp32 -> bf16
  uint32_t u = __float_as_uint(f);
  u += 0x7fffu + ((u >> 16) & 1u);
  return (ushort)(u >> 16);
}
__device__ inline void acc_bf4(uint2 v, float& a0, float& a1, float& a2, float& a3) {
  a0 += __uint_as_float(v.x << 16);
  a1 += __uint_as_float(v.x & 0xffff0000u);
  a2 += __uint_as_float(v.y << 16);
  a3 += __uint_as_float(v.y & 0xffff0000u);
}

// ---------- zero int array ----------
__global__ void zero_k(int* __restrict__ p, int n) {
  int i = blockIdx.x * NT + threadIdx.x;
  if (i < n) p[i] = 0;
}

// ---------- histogram of dst, both graphs in one dispatch ----------
__global__ void hist2_k(const int* __restrict__ e_dst, int E,
                        const int* __restrict__ c_dst, int EC,
                        int* __restrict__ cnt_c, int* __restrict__ cnt_t) {
  int i = blockIdx.x * NT + threadIdx.x;
  if (i < E) atomicAdd(&cnt_c[e_dst[i]], 1);
  else if (i < E + EC) atomicAdd(&cnt_t[c_dst[i - E]], 1);
}

// ---------- scan pass A ----------
__global__ __launch_bounds__(NT) void scan_partial_k(
    const int* __restrict__ cnt_c, const int* __restrict__ cnt_t, int n,
    int* __restrict__ bsum, int nb_c) {
  int isT = blockIdx.x >= nb_c;
  const int* cnt = isT ? cnt_t : cnt_c;
  int b = isT ? blockIdx.x - nb_c : blockIdx.x;
  int base = b * SCAN_ELEMS + threadIdx.x * 4;

  int s = 0;
  if (base + 3 < n) {
    int4 v = *(const int4*)&cnt[base];
    s = v.x + v.y + v.z + v.w;
  } else {
    for (int j = 0; j < 4; j++) if (base + j < n) s += cnt[base + j];
  }
  for (int off = 32; off > 0; off >>= 1) s += __shfl_down(s, off, 64);
  __shared__ int ws[4];
  int lane = threadIdx.x & 63, w = threadIdx.x >> 6;
  if (lane == 0) ws[w] = s;
  __syncthreads();
  if (threadIdx.x == 0) bsum[blockIdx.x] = ws[0] + ws[1] + ws[2] + ws[3];
}

// ---------- scan pass B ----------
__global__ __launch_bounds__(NT) void scan_offsets_k(
    int* __restrict__ bsum, int nb_c, int nb_t,
    int* __restrict__ rp_c, int* __restrict__ rp_t, int n) {
  int seg_off = (blockIdx.x == 0) ? 0 : nb_c;
  int nb = (blockIdx.x == 0) ? nb_c : nb_t;
  int* rp = (blockIdx.x == 0) ? rp_c : rp_t;

  __shared__ int ls[NT];
  int t = threadIdx.x;
  int v = (t < nb) ? bsum[seg_off + t] : 0;
  ls[t] = v;
  __syncthreads();
  for (int off = 1; off < NT; off <<= 1) {
    int u = (t >= off) ? ls[t - off] : 0;
    __syncthreads();
    ls[t] += u;
    __syncthreads();
  }
  if (t < nb) bsum[seg_off + t] = ls[t] - v;
  if (t == nb - 1) rp[n] = ls[t];
}

// ---------- scan pass C: rowptr out; also zeroes cnt (becomes fill cursor) ----------
__global__ __launch_bounds__(NT) void scan_final_k(
    int* __restrict__ cnt_c, int* __restrict__ cnt_t, int n,
    const int* __restrict__ bsum, int nb_c,
    int* __restrict__ rp_c, int* __restrict__ rp_t) {
  int isT = blockIdx.x >= nb_c;
  int* cnt = isT ? cnt_t : cnt_c;
  int* rp = isT ? rp_t : rp_c;
  int b = isT ? blockIdx.x - nb_c : blockIdx.x;
  int offset = bsum[blockIdx.x];
  int base = b * SCAN_ELEMS + threadIdx.x * 4;

  int4 v = make_int4(0, 0, 0, 0);
  if (base + 3 < n) v = *(const int4*)&cnt[base];
  else { if (base + 0 < n) v.x = cnt[base + 0];
         if (base + 1 < n) v.y = cnt[base + 1];
         if (base + 2 < n) v.z = cnt[base + 2];
         if (base + 3 < n) v.w = cnt[base + 3]; }
  int tsum = v.x + v.y + v.z + v.w;

  __shared__ int ls[NT];
  int t = threadIdx.x;
  ls[t] = tsum;
  __syncthreads();
  for (int off = 1; off < NT; off <<= 1) {
    int u = (t >= off) ? ls[t - off] : 0;
    __syncthreads();
    ls[t] += u;
    __syncthreads();
  }
  int excl = offset + ls[t] - tsum;

  int4 o;
  o.x = excl;
  o.y = o.x + v.x;
  o.z = o.y + v.y;
  o.w = o.z + v.z;
  if (base + 3 < n) {
    *(int4*)&rp[base] = o;
    *(int4*)&cnt[base] = make_int4(0, 0, 0, 0);   // cursor reset
  } else {
    if (base + 0 < n) { rp[base + 0] = o.x; cnt[base + 0] = 0; }
    if (base + 1 < n) { rp[base + 1] = o.y; cnt[base + 1] = 0; }
    if (base + 2 < n) { rp[base + 2] = o.z; cnt[base + 2] = 0; }
    if (base + 3 < n) { rp[base + 3] = o.w; cnt[base + 3] = 0; }
  }
}

// ---------- fill CSR, both graphs in one dispatch ----------
__global__ void fill2_k(const int* __restrict__ e_src, const int* __restrict__ e_dst, int E,
                        const int* __restrict__ c_src, const int* __restrict__ c_dst, int EC,
                        const int* __restrict__ rp_c, int* __restrict__ cur_c, int* __restrict__ csr_c,
                        const int* __restrict__ rp_t, int* __restrict__ cur_t, int* __restrict__ csr_t) {
  int i = blockIdx.x * NT + threadIdx.x;
  if (i < E) {
    int d = e_dst[i];
    csr_c[rp_c[d] + atomicAdd(&cur_c[d], 1)] = e_src[i];
  } else if (i < E + EC) {
    int j = i - E;
    int d = c_dst[j];
    csr_t[rp_t[d] + atomicAdd(&cur_t[d], 1)] = c_src[j];
  }
}

// ---------- dinv ----------
__global__ void dinv_k(const int* __restrict__ rp_c, float* __restrict__ dc,
                       const int* __restrict__ rp_t, float* __restrict__ dt, int n) {
  int i = blockIdx.x * NT + threadIdx.x;
  if (i < n) {
    dc[i] = rsqrtf((float)(rp_c[i + 1] - rp_c[i] + 1));
    dt[i] = rsqrtf((float)(rp_t[i + 1] - rp_t[i] + 1));
  }
}

// ---------- x fp32 -> bf16 ----------
__global__ void convx_k(const float* __restrict__ x, ushort* __restrict__ xh, int total4) {
  int i = blockIdx.x * NT + threadIdx.x;
  if (i < total4) {
    float4 v = ((const float4*)x)[i];
    ushort4 o;
    o.x = f2bf(v.x); o.y = f2bf(v.y); o.z = f2bf(v.z); o.w = f2bf(v.w);
    ((ushort4*)xh)[i] = o;
  }
}

// ---------- W fp32 [l][k][c] -> bf16 transposed wT[l][c][k] ----------
__global__ void convw_k(const float* __restrict__ Wc, const float* __restrict__ Wt,
                        ushort* __restrict__ wT) {
  int gid = blockIdx.x * NT + threadIdx.x;
  int l = gid >> 14, rem = gid & 16383;
  int c = rem >> 7, k = rem & 127;
  const float* W = (l < 4) ? (Wc + (size_t)l * 16384) : (Wt + (size_t)(l - 4) * 16384);
  wT[gid] = f2bf(W[k * DFEAT + c]);
}

// ---------- fused dual GEMM, bf16 MFMA, 2 row-frags per wave (B-frag reuse) ----------
__global__ __launch_bounds__(256, 2) void gemm2_k(
    const ushort* __restrict__ xh,
    const ushort* __restrict__ wTc, const ushort* __restrict__ wTt,
    const float* __restrict__ dinv_c, const float* __restrict__ dinv_t,
    ushort* __restrict__ t_c, ushort* __restrict__ t_t, int n) {
  __shared__ __align__(16) ushort Bc[DFEAT * BPAD];
  __shared__ __align__(16) ushort Bt[DFEAT * BPAD];
  int tid = threadIdx.x;

#pragma unroll
  for (int it = 0; it < 8; it++) {
    int idx = tid + it * NT;          // 0..2047: 128 rows x 16 uint4
    int c = idx >> 4, i = idx & 15;
    *(uint4*)&Bc[c * BPAD + i * 8] = *(const uint4*)&wTc[c * DFEAT + i * 8];
    *(uint4*)&Bt[c * BPAD + i * 8] = *(const uint4*)&wTt[c * DFEAT + i * 8];
  }
  __syncthreads();

  int wave = tid >> 6;
  int lane = tid & 63;
  int m = lane & 15;
  int q = lane >> 4;
  int row0 = blockIdx.x * GEMM_ROWS + wave * 32;
  int rowA = row0 + m;
  int rowB = row0 + 16 + m;

  f32x4 zero4 = {0.f, 0.f, 0.f, 0.f};
  f32x4 aC0[8], aC1[8], aT0[8], aT1[8];
#pragma unroll
  for (int i = 0; i < 8; i++) { aC0[i] = zero4; aC1[i] = zero4; aT0[i] = zero4; aT1[i] = zero4; }

#pragma unroll
  for (int ks = 0; ks < 4; ks++) {
    uint4 avA = make_uint4(0, 0, 0, 0), avB = make_uint4(0, 0, 0, 0);
    if (rowA < n) avA = *(const uint4*)&xh[(size_t)rowA * DFEAT + ks * 32 + q * 8];
    if (rowB < n) avB = *(const uint4*)&xh[(size_t)rowB * DFEAT + ks * 32 + q * 8];
    union { uint4 u; s8v s; } uA, uB; uA.u = avA; uB.u = avB;
#pragma unroll
    for (int c8 = 0; c8 < 8; c8++) {
      s8v bC = *(const s8v*)&Bc[(c8 * 16 + m) * BPAD + ks * 32 + q * 8];
      s8v bT = *(const s8v*)&Bt[(c8 * 16 + m) * BPAD + ks * 32 + q * 8];
      aC0[c8] = __builtin_amdgcn_mfma_f32_16x16x32_bf16(uA.s, bC, aC0[c8], 0, 0, 0);
      aC1[c8] = __builtin_amdgcn_mfma_f32_16x16x32_bf16(uB.s, bC, aC1[c8], 0, 0, 0);
      aT0[c8] = __builtin_amdgcn_mfma_f32_16x16x32_bf16(uA.s, bT, aT0[c8], 0, 0, 0);
      aT1[c8] = __builtin_amdgcn_mfma_f32_16x16x32_bf16(uB.s, bT, aT1[c8], 0, 0, 0);
    }
  }

  // epilogue: D row = q*4+r (within 16-row frag), col = c8*16+m
#pragma unroll
  for (int sub = 0; sub < 2; sub++) {
    int rbase = row0 + sub * 16 + q * 4;
#pragma unroll
    for (int r = 0; r < 4; r++) {
      int orow = rbase + r;
      if (orow < n) {
        float sc = dinv_c[orow], st = dinv_t[orow];
#pragma unroll
        for (int c8 = 0; c8 < 8; c8++) {
          int col = c8 * 16 + m;
          float vc = sub ? aC1[c8][r] : aC0[c8][r];
          float vt = sub ? aT1[c8][r] : aT0[c8][r];
          t_c[(size_t)orow * DFEAT + col] = f2bf(sc * vc);
          t_t[(size_t)orow * DFEAT + col] = f2bf(st * vt);
        }
      }
    }
  }
}

// ---------- per-graph gather with 4-wide MLP unroll ----------
__device__ inline void gather_graph(const ushort* __restrict__ t, const int* __restrict__ rp,
                                    const int* __restrict__ cs, int node, int lane, int c4,
                                    float& a0, float& a1, float& a2, float& a3) {
  acc_bf4(*(const uint2*)&t[(size_t)node * DFEAT + c4], a0, a1, a2, a3);  // self-loop
  int s0 = rp[node], s1 = rp[node + 1];
  for (int p = s0; p < s1; p += 32) {
    int mm = min(32, s1 - p);
    int sv = (lane < mm) ? cs[p + lane] : 0;
    int k = 0;
    for (; k + 4 <= mm; k += 4) {
      int sA = __shfl(sv, k, 32);
      int sB = __shfl(sv, k + 1, 32);
      int sC = __shfl(sv, k + 2, 32);
      int sD = __shfl(sv, k + 3, 32);
      uint2 vA = *(const uint2*)&t[(size_t)sA * DFEAT + c4];
      uint2 vB = *(const uint2*)&t[(size_t)sB * DFEAT + c4];
      uint2 vC = *(const uint2*)&t[(size_t)sC * DFEAT + c4];
      uint2 vD = *(const uint2*)&t[(size_t)sD * DFEAT + c4];
      acc_bf4(vA, a0, a1, a2, a3);
      acc_bf4(vB, a0, a1, a2, a3);
      acc_bf4(vC, a0, a1, a2, a3);
      acc_bf4(vD, a0, a1, a2, a3);
    }
    for (; k < mm; k++) {
      int s = __shfl(sv, k, 32);
      acc_bf4(*(const uint2*)&t[(size_t)s * DFEAT + c4], a0, a1, a2, a3);
    }
  }
}

// ---------- fused aggregate: both graphs + self + bias (+relu) ----------
__global__ __launch_bounds__(256) void aggregate_k(
    const ushort* __restrict__ tc, const ushort* __restrict__ tt,
    const int* __restrict__ rpc, const int* __restrict__ csc,
    const int* __restrict__ rpt, const int* __restrict__ cst,
    const float* __restrict__ dc, const float* __restrict__ dt,
    const float* __restrict__ bc, const float* __restrict__ bt,
    float* __restrict__ outf, ushort* __restrict__ outh, int n, int last) {
  int node = blockIdx.x * 8 + (threadIdx.x >> 5);
  if (node >= n) return;
  int lane = threadIdx.x & 31;
  int c4 = lane << 2;

  float a0 = 0.f, a1 = 0.f, a2 = 0.f, a3 = 0.f;
  gather_graph(tc, rpc, csc, node, lane, c4, a0, a1, a2, a3);
  float b0 = 0.f, b1 = 0.f, b2 = 0.f, b3 = 0.f;
  gather_graph(tt, rpt, cst, node, lane, c4, b0, b1, b2, b3);

  float sc = dc[node], st = dt[node];
  float4 bcv = *(const float4*)&bc[c4];
  float4 btv = *(const float4*)&bt[c4];
  float4 o;
  o.x = fmaf(sc, a0, fmaf(st, b0, bcv.x + btv.x));
  o.y = fmaf(sc, a1, fmaf(st, b1, bcv.y + btv.y));
  o.z = fmaf(sc, a2, fmaf(st, b2, bcv.z + btv.z));
  o.w = fmaf(sc, a3, fmaf(st, b3, bcv.w + btv.w));

  if (last) {
    *(float4*)&outf[(size_t)node * DFEAT + c4] = o;
  } else {
    ushort4 h;
    h.x = f2bf(fmaxf(o.x, 0.f));
    h.y = f2bf(fmaxf(o.y, 0.f));
    h.z = f2bf(fmaxf(o.z, 0.f));
    h.w = f2bf(fmaxf(o.w, 0.f));
    *(ushort4*)&outh[(size_t)node * DFEAT + c4] = h;
  }
}

extern "C" void kernel_launch(void* const* d_in, const int* in_sizes, int n_in,
                              void* d_out, int out_size, void* d_ws, size_t ws_size,
                              hipStream_t stream) {
  const float* x0 = (const float*)d_in[0];
  const int*   ei = (const int*)d_in[1];
  const int*   ci = (const int*)d_in[2];
  const float* Wc = (const float*)d_in[3];
  const float* bc = (const float*)d_in[4];
  const float* Wt = (const float*)d_in[5];
  const float* bt = (const float*)d_in[6];
  float* out = (float*)d_out;

  int n  = in_sizes[0] / DFEAT;     // 100000
  int E  = in_sizes[1] / 2;         // 600000
  int EC = in_sizes[2] / 2;         // 200000

  const int* e_src = ei;
  const int* e_dst = ei + E;
  const int* c_src = ci;
  const int* c_dst = ci + EC;

  char* p = (char*)d_ws;
  ushort* t_c = (ushort*)p; p += (size_t)n * DFEAT * 2;
  ushort* t_t = (ushort*)p; p += (size_t)n * DFEAT * 2;
  ushort* xh  = (ushort*)p; p += (size_t)n * DFEAT * 2;
  ushort* wT  = (ushort*)p; p += (size_t)8 * DFEAT * DFEAT * 2;
  float* dinv_c = (float*)p; p += (size_t)n * 4;
  float* dinv_t = (float*)p; p += (size_t)n * 4;
  int* cnt_c = (int*)p; p += (size_t)n * 4;
  int* cnt_t = (int*)p; p += (size_t)n * 4;
  int* rp_c  = (int*)p; p += (size_t)(n + 1) * 4;
  int* rp_t  = (int*)p; p += (size_t)(n + 1) * 4;
  int* csr_c = (int*)p; p += (size_t)E * 4;
  int* csr_t = (int*)p; p += (size_t)EC * 4;
  int* bsum  = (int*)p;

  int nb_n    = (n + NT - 1) / NT;
  int nb_node = (n + 7) / 8;
  int nb_gemm = (n + GEMM_ROWS - 1) / GEMM_ROWS;
  int nb_scan = (n + SCAN_ELEMS - 1) / SCAN_ELEMS;

  // ---- build CSR + dinv once per launch ----
  zero_k<<<(2 * n + NT - 1) / NT, NT, 0, stream>>>(cnt_c, 2 * n);
  hist2_k<<<(E + EC + NT - 1) / NT, NT, 0, stream>>>(e_dst, E, c_dst, EC, cnt_c, cnt_t);
  scan_partial_k<<<2 * nb_scan, NT, 0, stream>>>(cnt_c, cnt_t, n, bsum, nb_scan);
  scan_offsets_k<<<2, NT, 0, stream>>>(bsum, nb_scan, nb_scan, rp_c, rp_t, n);
  scan_final_k<<<2 * nb_scan, NT, 0, stream>>>(cnt_c, cnt_t, n, bsum, nb_scan, rp_c, rp_t);
  fill2_k<<<(E + EC + NT - 1) / NT, NT, 0, stream>>>(e_src, e_dst, E, c_src, c_dst, EC,
                                                     rp_c, cnt_c, csr_c, rp_t, cnt_t, csr_t);
  dinv_k<<<nb_n, NT, 0, stream>>>(rp_c, dinv_c, rp_t, dinv_t, n);

  // ---- bf16 conversions ----
  convx_k<<<(n * 32 + NT - 1) / NT, NT, 0, stream>>>(x0, xh, n * 32);
  convw_k<<<(8 * DFEAT * DFEAT) / NT, NT, 0, stream>>>(Wc, Wt, wT);

  // ---- layers ----
  for (int i = 0; i < 4; i++) {
    gemm2_k<<<nb_gemm, NT, 0, stream>>>(xh,
                                        wT + (size_t)i * DFEAT * DFEAT,
                                        wT + (size_t)(4 + i) * DFEAT * DFEAT,
                                        dinv_c, dinv_t, t_c, t_t, n);
    aggregate_k<<<nb_node, NT, 0, stream>>>(t_c, t_t, rp_c, csr_c, rp_t, csr_t,
                                            dinv_c, dinv_t, bc + i * DFEAT, bt + i * DFEAT,
                                            out, xh, n, (i == 3) ? 1 : 0);
  }
}